// Round 1
// 332.986 us; speedup vs baseline: 1.0312x; 1.0312x over previous
//
#include <hip/hip_runtime.h>
#include <cstdint>
#include <cstddef>

#define INPUT_DIM 784
#define HIDDEN    4096
#define BATCH     64
#define T_STEPS   30
#define N0 (BATCH*INPUT_DIM)   // 50176
#define N1 (BATCH*HIDDEN)      // 262144
#define M_ROWS (T_STEPS*BATCH) // 1920
#define NDIG 4
#define MB_CNT (M_ROWS/32)     // 60
#define KC1 25                 // gemm1 k-chunks (784 padded to 800)
#define KC2 128                // gemm2 k-chunks

typedef int v4i  __attribute__((ext_vector_type(4)));
typedef int v16i __attribute__((ext_vector_type(16)));

// ---------------- max(x) reduction (unchanged, passing) --------------------
__global__ __launch_bounds__(256) void max_kernel(const float* __restrict__ x,
                                                  unsigned* __restrict__ maxbits) {
    int i = blockIdx.x * 256 + threadIdx.x;
    float v = (i < N0) ? x[i] : 0.0f;
    #pragma unroll
    for (int off = 32; off > 0; off >>= 1)
        v = fmaxf(v, __shfl_down(v, off, 64));
    __shared__ float sm[4];
    int lane = threadIdx.x & 63;
    int wv   = threadIdx.x >> 6;
    if (lane == 0) sm[wv] = v;
    __syncthreads();
    if (threadIdx.x == 0) {
        float m = fmaxf(fmaxf(sm[0], sm[1]), fmaxf(sm[2], sm[3]));
        atomicMax(maxbits, __float_as_uint(m));
    }
}

// ---------------- layer 0 LIF: same math (passing), spikes -> A-fragments --
// AF1[kc][mb][lane][16], lane=(b&31)|(((j>>4)&1)<<5), mb=2t+(b>>5), byte=j&15.
__global__ __launch_bounds__(256) void lif0_kernel(const float* __restrict__ x,
                                                   const unsigned* __restrict__ maxbits,
                                                   uint8_t* __restrict__ AF1,
                                                   float* __restrict__ out0) {
    int j = blockIdx.x * 256 + threadIdx.x;   // input-dim index
    int b = blockIdx.y;                        // batch
    if (j >= INPUT_DIM) return;
    float mx = fmaxf(__uint_as_float(*maxbits), 1e-12f);
    float xs = __fmul_rn(__fdiv_rn(x[b * INPUT_DIM + j], mx), 16.0f);
    int kc = j >> 5;
    int lane = (b & 31) | (((j >> 4) & 1) << 5);
    size_t base = (((size_t)(kc * MB_CNT + (b >> 5)) * 64 + lane) << 4) + (j & 15);
    float v = 0.0f;
    int cnt = 0;
    #pragma unroll
    for (int t = 0; t < T_STEPS; ++t) {
        v = __fadd_rn(__fmul_rn(v, 0.99f), xs);
        int s = (v >= 0.5f) ? 1 : 0;
        cnt += s;
        v = s ? 0.0f : v;
        AF1[base + (size_t)t * 2048] = (uint8_t)s;
    }
    out0[b * INPUT_DIM + j] = (float)cnt / 30.0f;
}

// ---------------- W -> 4 digit planes in MFMA B-fragment order -------------
// q = round(W * scale); 4 signed base-256 digits; per-elem err <= 1/(2*scale).
// BF[nb][kc][d][lane][16]; rows k >= Krows are zero (gemm1 K padding).
__global__ __launch_bounds__(256) void digitize_kernel(const float* __restrict__ W,
                                                       int8_t* __restrict__ BF,
                                                       int Krows, int KC, double scale) {
    __shared__ float tile[32][33];
    const int nb = blockIdx.x, kc = blockIdx.y;
    const int tid = threadIdx.x;
    {
        int r  = tid >> 3;
        int c4 = (tid & 7) << 2;
        int k  = kc * 32 + r;
        float4 w4 = make_float4(0.f, 0.f, 0.f, 0.f);
        if (k < Krows)
            w4 = *(const float4*)&W[(size_t)k * HIDDEN + nb * 32 + c4];
        tile[r][c4]     = w4.x;
        tile[r][c4 + 1] = w4.y;
        tile[r][c4 + 2] = w4.z;
        tile[r][c4 + 3] = w4.w;
    }
    __syncthreads();
    const int d    = tid >> 6;        // wave -> digit plane
    const int lane = tid & 63;
    const int nl   = lane & 31;
    const int kh   = (lane >> 5) << 4;
    char dig[16];
    #pragma unroll
    for (int jj = 0; jj < 16; ++jj) {
        double w = (double)tile[kh + jj][nl];
        long long q = __double2ll_rn(w * scale);
        int dd = 0;
        #pragma unroll
        for (int dd_i = 0; dd_i <= 3; ++dd_i) {
            dd = (int)(((q + 128) & 255) - 128);
            q = (q - (long long)dd) >> 8;
            if (dd_i == d) break;
        }
        dig[jj] = (char)dd;
    }
    *(int4*)&BF[((((size_t)nb * KC + kc) * NDIG + d) << 10) + (lane << 4)] =
        *(int4*)&dig[0];
}

// ---------------- exact i8-digit streaming GEMM (both layers) --------------
// C(1920 x 4096 f64) = A(binary) @ W, 4 digit planes, no LDS, no barriers.
// Depth-2 register pipeline, COPY-FREE rotation: each iteration first issues
// the MFMA group consuming slot s (loaded 2 iters ago -> wait is vmcnt(6),
// ~1170 cyc of cover), then loads chunk kc+2 DIRECTLY into slot s (safe WAR:
// MFMA reads operands at issue). The previous version staged loads in temps
// and copied them into the slots after the MFMAs -- those v_movs forced a
// same-iteration vmcnt wait, exposing ~750 cyc of L2/LLC latency per iter
// (measured: 1360 cyc/iter vs 584 cyc of MFMA demand -> MfmaUtil 42%).
// Main loop count forced even so slot indices stay compile-time for both
// KC=128 and KC=25 (no peeled iteration -> no runtime-indexed array ->
// no scratch). XCD-clustered swizzle unchanged (8 MB B footprint per XCD).
#define MFMA_GRP(A0, A1, B0, B1, B2, B3)                                        \
    acc[0][0] = __builtin_amdgcn_mfma_i32_32x32x32_i8(A0, B0, acc[0][0], 0, 0, 0); \
    acc[1][0] = __builtin_amdgcn_mfma_i32_32x32x32_i8(A1, B0, acc[1][0], 0, 0, 0); \
    acc[0][1] = __builtin_amdgcn_mfma_i32_32x32x32_i8(A0, B1, acc[0][1], 0, 0, 0); \
    acc[1][1] = __builtin_amdgcn_mfma_i32_32x32x32_i8(A1, B1, acc[1][1], 0, 0, 0); \
    acc[0][2] = __builtin_amdgcn_mfma_i32_32x32x32_i8(A0, B2, acc[0][2], 0, 0, 0); \
    acc[1][2] = __builtin_amdgcn_mfma_i32_32x32x32_i8(A1, B2, acc[1][2], 0, 0, 0); \
    acc[0][3] = __builtin_amdgcn_mfma_i32_32x32x32_i8(A0, B3, acc[0][3], 0, 0, 0); \
    acc[1][3] = __builtin_amdgcn_mfma_i32_32x32x32_i8(A1, B3, acc[1][3], 0, 0, 0)

#define LOAD_SLOT(S)                                                            \
    As[S][0] = *(const v4i*)ap;          As[S][1] = *(const v4i*)(ap + 1024);   \
    Bs[S][0] = *(const v4i*)bp;          Bs[S][1] = *(const v4i*)(bp + 1024);   \
    Bs[S][2] = *(const v4i*)(bp + 2048); Bs[S][3] = *(const v4i*)(bp + 3072)

#define MFMA_SLOT(S) MFMA_GRP(As[S][0], As[S][1], Bs[S][0], Bs[S][1], Bs[S][2], Bs[S][3])

template <int KC>
__global__ __launch_bounds__(256, 2) void gemm_i8_kernel(const int8_t* __restrict__ AF,
                                                         const int8_t* __restrict__ BF,
                                                         double* __restrict__ C,
                                                         double scale) {
    const int tid  = threadIdx.x;
    const int wave = tid >> 6, lane = tid & 63;
    const int i  = blockIdx.x;
    const int bx = i >> 6;                            // 0..14
    const int by = ((i & 7) << 3) | ((i >> 3) & 7);   // XCD-clustered n-block
    const int nb  = by * 2 + (wave & 1);
    const int msb = (wave >> 1) * 2;
    const int mb0 = bx * 4 + msb;

    const int8_t* ap = AF + (((size_t)mb0 * 64 + lane) << 4);
    const int8_t* bp = BF + (((size_t)nb * KC * NDIG) << 10) + (lane << 4);
    const int astride = MB_CNT * 64 * 16;   // 61440
    const int bstride = NDIG * 1024;        // 4096

    v16i acc[2][4] = {};
    v4i As[2][2], Bs[2][4];

    LOAD_SLOT(0);                           // chunk 0
    ap += astride; bp += bstride;
    LOAD_SLOT(1);                           // chunk 1

    // main loop: even iteration count, compile-time slot index everywhere.
    // iter kc: consume chunk kc (slot kc&1), then prefetch chunk kc+2 into
    // the same slot. Last prefetched chunk is KCE+1 <= KC-1.
    constexpr int KCE = (KC - 2) & ~1;      // 126 for KC=128, 22 for KC=25
    #pragma unroll 2
    for (int kc = 0; kc < KCE; ++kc) {
        const int s = kc & 1;
        if (s == 0) { MFMA_SLOT(0); } else { MFMA_SLOT(1); }
        ap += astride; bp += bstride;
        if (s == 0) { LOAD_SLOT(0); } else { LOAD_SLOT(1); }
    }

    if constexpr ((KC & 1) == 0) {
        // slots hold chunks KCE (slot 0), KCE+1 (slot 1)
        MFMA_SLOT(0);
        MFMA_SLOT(1);
    } else {
        // slots hold chunks KCE (slot 0), KCE+1 (slot 1); chunk KCE+2 remains
        MFMA_SLOT(0);                       // chunk KCE
        ap += astride; bp += bstride;
        LOAD_SLOT(0);                       // chunk KCE+2 -> slot 0
        MFMA_SLOT(1);                       // chunk KCE+1
        MFMA_SLOT(0);                       // chunk KCE+2
    }

    // epilogue: C/D layout col=lane&31, row=(r&3)+8*(r>>2)+4*(lane>>5)
    const int col = lane & 31;
    const int rb  = (lane >> 5) << 2;
    const int n_g = by * 64 + (wave & 1) * 32 + col;
    #pragma unroll
    for (int s = 0; s < 2; ++s) {
        const int m_base = bx * 128 + (msb + s) * 32;
        #pragma unroll
        for (int r = 0; r < 16; ++r) {
            int row = (r & 3) + 8 * (r >> 2) + rb;
            long long v = 0;
            #pragma unroll
            for (int d = 3; d >= 0; --d) v = (v << 8) + (long long)acc[s][d][r];
            C[(size_t)(m_base + row) * HIDDEN + n_g] = (double)v * scale;
        }
    }
}

// ---------------- layer 1 LIF: f64 currents, spikes -> A-fragments ---------
__global__ __launch_bounds__(256) void lif1_kernel(const double* __restrict__ CUR,
                                                   uint8_t* __restrict__ AF,
                                                   float* __restrict__ out1) {
    int e = blockIdx.x * 256 + threadIdx.x;
    int b = e >> 12;
    int j = e & 4095;
    int kc = j >> 5;
    int lane = (b & 31) | (((j >> 4) & 1) << 5);
    size_t base = (((size_t)(kc * MB_CNT + (b >> 5)) * 64 + lane) << 4) + (j & 15);
    double v = 0.0;
    int cnt = 0;
    #pragma unroll
    for (int t = 0; t < T_STEPS; ++t) {
        double cur = CUR[(size_t)t * N1 + e];
        v = __dadd_rn(__dmul_rn(v, 0.99), cur);
        int s = (v >= 0.5) ? 1 : 0;
        cnt += s;
        v = s ? 0.0 : v;
        AF[base + (size_t)t * 2048] = (uint8_t)s;
    }
    out1[e] = (float)cnt / 30.0f;
}

// ---------------- layer 2 LIF in fp64 (unchanged, passing) -----------------
__global__ __launch_bounds__(256) void lif2_kernel(const double* __restrict__ CUR,
                                                   float* __restrict__ out2) {
    int e = blockIdx.x * 256 + threadIdx.x;
    double v = 0.0;
    int cnt = 0;
    #pragma unroll
    for (int t = 0; t < T_STEPS; ++t) {
        double cur = CUR[(size_t)t * N1 + e];
        v = __dadd_rn(__dmul_rn(v, 0.99), cur);
        int s = (v >= 0.5) ? 1 : 0;
        cnt += s;
        v = s ? 0.0 : v;
    }
    out2[e] = (float)cnt / 30.0f;
}

extern "C" void kernel_launch(void* const* d_in, const int* in_sizes, int n_in,
                              void* d_out, int out_size, void* d_ws, size_t ws_size,
                              hipStream_t stream) {
    const float* x  = (const float*)d_in[0];
    const float* W1 = (const float*)d_in[1];   // 784 x 4096
    const float* W2 = (const float*)d_in[2];   // 4096 x 4096
    float* out = (float*)d_out;
    char*  ws  = (char*)d_ws;

    // workspace (~153 MB):
    // [maxbits 256B][AF1 1.54MB][BF1 12.8MB][AF2 7.86MB][BF2 64MB][CURd 62.9MB]
    const size_t AF1_SZ = (size_t)KC1 * MB_CNT * 1024;           // 1,536,000
    const size_t BF1_SZ = (size_t)128 * KC1 * NDIG * 1024;       // 12.8 MB
    const size_t AF2_SZ = (size_t)KC2 * MB_CNT * 1024;           // 7.86 MB
    const size_t BF2_SZ = (size_t)128 * KC2 * NDIG * 1024;       // 64 MB
    unsigned* maxbits = (unsigned*)ws;
    uint8_t*  AF1 = (uint8_t*)(ws + 256);
    int8_t*   BF1 = (int8_t*)(AF1 + AF1_SZ);
    uint8_t*  AF2 = (uint8_t*)(BF1 + BF1_SZ);
    int8_t*   BF2 = (int8_t*)(AF2 + AF2_SZ);
    double*   CURd = (double*)((char*)BF2 + BF2_SZ);

    float* out0 = out;
    float* out1 = out + N0;
    float* out2 = out + N0 + N1;

    hipMemsetAsync(maxbits, 0, 4, stream);
    hipMemsetAsync(AF1, 0, AF1_SZ, stream);   // K-padding rows 784..799 stay 0
    max_kernel <<<(N0 + 255) / 256, 256, 0, stream>>>(x, maxbits);
    lif0_kernel<<<dim3(4, BATCH), 256, 0, stream>>>(x, maxbits, AF1, out0);
    digitize_kernel<<<dim3(128, KC1), 256, 0, stream>>>(W1, BF1, INPUT_DIM, KC1,
                                                        4294967296.0);      // 2^32
    digitize_kernel<<<dim3(128, KC2), 256, 0, stream>>>(W2, BF2, HIDDEN, KC2,
                                                        8589934592.0);      // 2^33
    gemm_i8_kernel<KC1><<<960, 256, 0, stream>>>((const int8_t*)AF1, BF1, CURd,
                                                 2.3283064365386963e-10);   // 2^-32
    lif1_kernel<<<N1 / 256, 256, 0, stream>>>(CURd, AF2, out1);
    gemm_i8_kernel<KC2><<<960, 256, 0, stream>>>((const int8_t*)AF2, BF2, CURd,
                                                 1.1641532182693481e-10);   // 2^-33
    lif2_kernel<<<N1 / 256, 256, 0, stream>>>(CURd, out2);
}